// Round 1
// baseline (2187.560 us; speedup 1.0000x reference)
//
#include <hip/hip_runtime.h>
#include <hip/hip_bf16.h>

// ---- static problem config ----
constexpr int B_    = 8;
constexpr int L1_   = 7;
constexpr int L2_   = 3;
constexpr int N1_   = 2048;
constexpr int N2_   = 512;
constexpr int CIN_  = 512;
constexpr int MID_  = 256;
constexpr int OUT_  = 512;
constexpr int CORIG_= 128;
constexpr int K_    = 3;
constexpr int TFC_  = K_ * MID_;   // 768
constexpr int CTOT_ = MID_ + CORIG_; // 384

// -------------------------------------------------------------------------
// Kernel 1: temporal 1x1 conv -> tf[b][l2][o][n2], o in [0,768)
// C = Wt (768x512) x features[b,l2] (512x512)
// 128x128 block tile, 8x8 micro-tile (4+4 slabs at +0/+64).
// Accumulation order per output element: sequential K ascending fp32 FMA —
// bit-identical to the previous 64x64/4x4 version.
// -------------------------------------------------------------------------
__global__ __launch_bounds__(256) void tconv_gemm(const float* __restrict__ feat,
                                                  const float* __restrict__ Wt,
                                                  float* __restrict__ tf)
{
    __shared__ float As[16][132];  // As[j][i] = Wt[o0+i][kk+j]; +4 pad kills write conflicts
    __shared__ float Bs[16][128];  // Bs[j][i] = feat[kk+j][n0+i]
    const int tid = threadIdx.x;
    const int n0 = blockIdx.x * 128;
    const int o0 = blockIdx.y * 128;
    const int batch = blockIdx.z;          // b*L2 + l2
    const float* Bp = feat + (size_t)batch * CIN_ * N2_;
    float acc[8][8] = {};
    const int tx = tid & 15, ty = tid >> 4;
    for (int kk = 0; kk < CIN_; kk += 16) {
        #pragma unroll
        for (int r = 0; r < 8; r++) {
            int e = tid + r * 256;
            int i = e >> 4, j = e & 15;    // 16 consecutive lanes read 16 contiguous Wt floats
            As[j][i] = Wt[(size_t)(o0 + i) * CIN_ + kk + j];
        }
        #pragma unroll
        for (int r = 0; r < 8; r++) {
            int e = tid + r * 256;
            int j = e >> 7, i = e & 127;   // coalesced row reads, conflict-free LDS writes
            Bs[j][i] = Bp[(size_t)(kk + j) * N2_ + n0 + i];
        }
        __syncthreads();
        #pragma unroll
        for (int j = 0; j < 16; j++) {
            float a[8], bb[8];
            #pragma unroll
            for (int r = 0; r < 4; r++) { a[r]  = As[j][ty * 4 + r];
                                          a[r+4]= As[j][64 + ty * 4 + r]; }
            #pragma unroll
            for (int c = 0; c < 4; c++) { bb[c]  = Bs[j][tx * 4 + c];
                                          bb[c+4]= Bs[j][64 + tx * 4 + c]; }
            #pragma unroll
            for (int r = 0; r < 8; r++)
                #pragma unroll
                for (int c = 0; c < 8; c++)
                    acc[r][c] += a[r] * bb[c];
        }
        __syncthreads();
    }
    float* Cp = tf + (size_t)batch * TFC_ * N2_;
    #pragma unroll
    for (int rh = 0; rh < 2; rh++)
        #pragma unroll
        for (int r = 0; r < 4; r++) {
            int o = o0 + rh * 64 + ty * 4 + r;
            #pragma unroll
            for (int ch = 0; ch < 2; ch++) {
                float4 v = make_float4(acc[rh*4+r][ch*4+0], acc[rh*4+r][ch*4+1],
                                       acc[rh*4+r][ch*4+2], acc[rh*4+r][ch*4+3]);
                *(float4*)&Cp[(size_t)o * N2_ + n0 + ch * 64 + tx * 4] = v;
            }
        }
}

// -------------------------------------------------------------------------
// Kernel 2: BN statistics per channel-slice ch = l2*768 + o (2304 blocks)
// -------------------------------------------------------------------------
__global__ __launch_bounds__(256) void bn_stats(const float* __restrict__ tf,
                                                const float* __restrict__ gamma,
                                                const float* __restrict__ beta,
                                                float* __restrict__ scale,
                                                float* __restrict__ shift)
{
    const int ch = blockIdx.x;          // l2*TFC_ + o
    const int l2 = ch / TFC_;
    const int o  = ch % TFC_;
    const int mid = o % MID_;           // channel index within MID for gamma/beta
    const int tid = threadIdx.x;
    float s = 0.f, sq = 0.f;
    #pragma unroll
    for (int t = 0; t < 16; t++) {
        int v = tid + t * 256;          // 0..4095
        int b = v >> 9, n2 = v & 511;
        float x = tf[((size_t)(b * L2_ + l2) * TFC_ + o) * N2_ + n2];
        s += x; sq += x * x;
    }
    __shared__ float ss[256], sqs[256];
    ss[tid] = s; sqs[tid] = sq;
    __syncthreads();
    for (int st = 128; st > 0; st >>= 1) {
        if (tid < st) { ss[tid] += ss[tid + st]; sqs[tid] += sqs[tid + st]; }
        __syncthreads();
    }
    if (tid == 0) {
        float mean = ss[0] * (1.f / 4096.f);
        float var = fmaxf(sqs[0] * (1.f / 4096.f) - mean * mean, 0.f);
        float sc = gamma[mid] * rsqrtf(var + 1e-5f);
        scale[ch] = sc;
        shift[ch] = beta[mid] - mean * sc;
    }
}

// -------------------------------------------------------------------------
// Kernel 3: apply BN + ReLU in place on tf (9437184 elements)
// -------------------------------------------------------------------------
__global__ __launch_bounds__(256) void bn_apply(float* __restrict__ tf,
                                                const float* __restrict__ scale,
                                                const float* __restrict__ shift)
{
    int idx = blockIdx.x * 256 + threadIdx.x;
    int ch = (idx >> 9) % (L2_ * TFC_);
    float x = tf[idx];
    tf[idx] = fmaxf(x * scale[ch] + shift[ch], 0.f);
}

// -------------------------------------------------------------------------
// Kernel 4: 3-NN search + weights.
// Replicates the XLA:CPU fp32 arithmetic of the reference:
//   d2 = (|a|^2 + |n|^2) - 2*dot,  dot via Eigen-style ASCENDING FMA CHAIN
//   dot = fma(az*nz, fma(ay*ny, rn(ax*nx)))   <- the one free rounding choice
// norms/reduce and elementwise combine are separate per-op-rounded fp32 (HLO
// semantics). Only the top-3 SET matters (weighted sum is order-invariant),
// and the set is decided by these exact roundings at the 3rd/4th boundary.
// History: exact f64 selection -> absmax 0.566; no-FMA expanded -> 0.651.
// -------------------------------------------------------------------------
__global__ __launch_bounds__(256) void three_nn_kernel(const float* __restrict__ xyzs,
                                                       const float* __restrict__ oxyzs,
                                                       int* __restrict__ fbbuf,
                                                       float* __restrict__ wbuf)
{
    // temporal transpose gather table (t1 0-based)
    const int nsegs[7]  = {1, 1, 2, 1, 2, 1, 1};
    const int t2s[7][2] = {{0,0},{0,0},{0,1},{1,1},{1,2},{2,2},{2,2}};
    const int kks[7][2] = {{0,0},{1,1},{2,0},{1,1},{2,0},{1,1},{2,2}};

    const int tid = threadIdx.x;
    const int t1 = blockIdx.y;
    const int b  = blockIdx.z;
    const int M = nsegs[t1] * N2_;

    __shared__ float sx[1024], sy[1024], sz[1024], sn2[1024];
    for (int j = tid; j < M; j += 256) {
        int seg = j >> 9;
        int t2 = t2s[t1][seg];
        const float* p = xyzs + ((size_t)(b * L2_ + t2) * N2_ + (j & 511)) * 3;
        float x = p[0], y = p[1], z = p[2];
        sx[j] = x; sy[j] = y; sz[j] = z;
        // |n|^2 = ((x*x + y*y) + z*z), each op rounded fp32, no FMA (XLA reduce)
        sn2[j] = __fadd_rn(__fadd_rn(__fmul_rn(x, x), __fmul_rn(y, y)),
                           __fmul_rn(z, z));
    }
    __syncthreads();

    const int n1 = blockIdx.x * 256 + tid;
    const float* a = oxyzs + ((size_t)(b * L1_ + t1) * N1_ + n1) * 3;
    const float ax = a[0], ay = a[1], az = a[2];
    const float an2 = __fadd_rn(__fadd_rn(__fmul_rn(ax, ax), __fmul_rn(ay, ay)),
                                __fmul_rn(az, az));

    float d0 = 1e30f, d1 = 1e30f, d2v = 1e30f;
    int i0 = 0, i1 = 0, i2 = 0;
    for (int j = 0; j < M; j++) {
        // Eigen gemm K-loop: acc=0; acc=fma(a_k,b_k,acc) ascending ->
        // dot = rn(az*nz + rn(ay*ny + rn(ax*nx)))
        float dot = fmaf(az, sz[j], fmaf(ay, sy[j], __fmul_rn(ax, sx[j])));
        // d2 = (an2 + nn2) - rn(2*dot), separate HLO roundings
        float d = __fsub_rn(__fadd_rn(an2, sn2[j]), __fmul_rn(2.0f, dot));
        // stable ascending insertion (ties keep lower index) == top_k(-d2,3)
        if (d < d0)       { d2v = d1; i2 = i1; d1 = d0; i1 = i0; d0 = d; i0 = j; }
        else if (d < d1)  { d2v = d1; i2 = i1; d1 = d;  i1 = j; }
        else if (d < d2v) { d2v = d;  i2 = j; }
    }
    // dist = sqrt(max(d2, 1e-12)); w = 1/(dist + 1e-8); w /= sum(w)  — fp32
    float dist0 = sqrtf(fmaxf(d0,  1e-12f));
    float dist1 = sqrtf(fmaxf(d1,  1e-12f));
    float dist2 = sqrtf(fmaxf(d2v, 1e-12f));
    float w0 = 1.0f / __fadd_rn(dist0, 1e-8f);
    float w1 = 1.0f / __fadd_rn(dist1, 1e-8f);
    float w2 = 1.0f / __fadd_rn(dist2, 1e-8f);
    float wsum = __fadd_rn(__fadd_rn(w0, w1), w2);
    w0 = w0 / wsum; w1 = w1 / wsum; w2 = w2 / wsum;

    size_t base = ((size_t)(b * L1_ + t1) * N1_ + n1) * 3;
    int   idxs[3] = {i0, i1, i2};
    float wws[3]  = {w0, w1, w2};
    #pragma unroll
    for (int j = 0; j < 3; j++) {
        int seg = idxs[j] >> 9;
        int t2 = t2s[t1][seg];
        int k  = kks[t1][seg];
        fbbuf[base + j] = ((b * L2_ + t2) * K_ + k) * (MID_ * N2_) + (idxs[j] & 511);
        wbuf[base + j]  = wws[j];
    }
}

// -------------------------------------------------------------------------
// Kernel 5: spatial 1x1 conv with fused 3-NN gather + concat.
// Per (b,t1): C(512x2048) = Ws(512x384) x nf(384x2048),
// nf rows 0..255 gathered from sf via (fb, w), rows 256..383 from orig feats.
// 128x128 block tile, 8x8 micro-tile — gather redundancy 8x -> 4x, LDS
// reads conflict-free (broadcast / contiguous-16B patterns).
// Per-output accumulation chain identical to previous version (bit-exact).
// -------------------------------------------------------------------------
__global__ __launch_bounds__(256) void sconv_gemm(const float* __restrict__ sf,
                                                  const float* __restrict__ of,
                                                  const float* __restrict__ Ws,
                                                  const int* __restrict__ fbbuf,
                                                  const float* __restrict__ wbuf,
                                                  float* __restrict__ outp)
{
    __shared__ float As[16][132];
    __shared__ float Bs[16][128];
    __shared__ int   sFB[384];
    __shared__ float sW[384];
    const int tid = threadIdx.x;
    const int n0 = blockIdx.x * 128;
    const int o0 = blockIdx.y * 128;
    const int bt = blockIdx.z;             // b*L1 + t1

    for (int t = tid; t < 384; t += 256) {
        size_t gbase = ((size_t)bt * N1_ + n0) * 3;
        sFB[t] = fbbuf[gbase + t];
        sW[t]  = wbuf [gbase + t];
    }
    __syncthreads();

    float acc[8][8] = {};
    const int tx = tid & 15, ty = tid >> 4;
    const float* ofp = of + (size_t)bt * CORIG_ * N1_;

    for (int kk = 0; kk < CTOT_; kk += 16) {
        #pragma unroll
        for (int r = 0; r < 8; r++) {
            int e = tid + r * 256;
            int i = e >> 4, j = e & 15;
            As[j][i] = Ws[(size_t)(o0 + i) * CTOT_ + kk + j];
        }
        #pragma unroll
        for (int r = 0; r < 8; r++) {
            int e = tid + r * 256;
            int j = e >> 7, i = e & 127;
            int c = kk + j;                // branch uniform per kk step (MID_%16==0)
            float v;
            if (c < MID_) {
                int gb = i * 3;
                size_t co = (size_t)c * N2_;
                v = sW[gb]     * sf[(size_t)sFB[gb]     + co]
                  + sW[gb + 1] * sf[(size_t)sFB[gb + 1] + co]
                  + sW[gb + 2] * sf[(size_t)sFB[gb + 2] + co];
            } else {
                v = ofp[(size_t)(c - MID_) * N1_ + n0 + i];
            }
            Bs[j][i] = v;
        }
        __syncthreads();
        #pragma unroll
        for (int j = 0; j < 16; j++) {
            float a[8], bb[8];
            #pragma unroll
            for (int r = 0; r < 4; r++) { a[r]  = As[j][ty * 4 + r];
                                          a[r+4]= As[j][64 + ty * 4 + r]; }
            #pragma unroll
            for (int c = 0; c < 4; c++) { bb[c]  = Bs[j][tx * 4 + c];
                                          bb[c+4]= Bs[j][64 + tx * 4 + c]; }
            #pragma unroll
            for (int r = 0; r < 8; r++)
                #pragma unroll
                for (int c = 0; c < 8; c++)
                    acc[r][c] += a[r] * bb[c];
        }
        __syncthreads();
    }
    float* Cp = outp + (size_t)bt * OUT_ * N1_;
    #pragma unroll
    for (int rh = 0; rh < 2; rh++)
        #pragma unroll
        for (int r = 0; r < 4; r++) {
            int o = o0 + rh * 64 + ty * 4 + r;
            #pragma unroll
            for (int ch = 0; ch < 2; ch++) {
                float4 v = make_float4(acc[rh*4+r][ch*4+0], acc[rh*4+r][ch*4+1],
                                       acc[rh*4+r][ch*4+2], acc[rh*4+r][ch*4+3]);
                *(float4*)&Cp[(size_t)o * N1_ + n0 + ch * 64 + tx * 4] = v;
            }
        }
}

// -------------------------------------------------------------------------
extern "C" void kernel_launch(void* const* d_in, const int* in_sizes, int n_in,
                              void* d_out, int out_size, void* d_ws, size_t ws_size,
                              hipStream_t stream)
{
    const float* xyzs  = (const float*)d_in[0];  // (B, L2, N2, 3)
    const float* oxyzs = (const float*)d_in[1];  // (B, L1, N1, 3)
    const float* feats = (const float*)d_in[2];  // (B, L2, CIN, N2)
    const float* ofeat = (const float*)d_in[3];  // (B, L1, CORIG, N1)
    const float* Wt    = (const float*)d_in[4];  // (768, 512)
    const float* gamma = (const float*)d_in[5];  // (256,)
    const float* beta  = (const float*)d_in[6];  // (256,)
    const float* Ws    = (const float*)d_in[7];  // (512, 384)
    float* out = (float*)d_out;

    // workspace layout
    char* ws = (char*)d_ws;
    float* tf    = (float*)ws;                                   // 9437184 f = 37748736 B
    float* scale = (float*)(ws + 37748736);                      // 2304 f
    float* shift = scale + 2304;                                 // 2304 f
    int*   fbbuf = (int*)(ws + 37748736 + 18432);                // 344064 i
    float* wbuf  = (float*)(ws + 37748736 + 18432 + 1376256);    // 344064 f

    // Output 0: original_xyzs passthrough
    hipMemcpyAsync(out, oxyzs, (size_t)B_ * L1_ * N1_ * 3 * sizeof(float),
                   hipMemcpyDeviceToDevice, stream);
    float* out_nf = out + (size_t)B_ * L1_ * N1_ * 3;

    tconv_gemm<<<dim3(N2_ / 128, TFC_ / 128, B_ * L2_), 256, 0, stream>>>(feats, Wt, tf);
    bn_stats<<<L2_ * TFC_, 256, 0, stream>>>(tf, gamma, beta, scale, shift);
    bn_apply<<<(B_ * L2_ * TFC_ * N2_) / 256, 256, 0, stream>>>(tf, scale, shift);
    three_nn_kernel<<<dim3(N1_ / 256, L1_, B_), 256, 0, stream>>>(xyzs, oxyzs, fbbuf, wbuf);
    sconv_gemm<<<dim3(N1_ / 128, OUT_ / 128, B_ * L1_), 256, 0, stream>>>(tf, ofeat, Ws, fbbuf, wbuf, out_nf);
}

// Round 2
// 1608.361 us; speedup vs baseline: 1.3601x; 1.3601x over previous
//
#include <hip/hip_runtime.h>
#include <hip/hip_bf16.h>

// ---- static problem config ----
constexpr int B_    = 8;
constexpr int L1_   = 7;
constexpr int L2_   = 3;
constexpr int N1_   = 2048;
constexpr int N2_   = 512;
constexpr int CIN_  = 512;
constexpr int MID_  = 256;
constexpr int OUT_  = 512;
constexpr int CORIG_= 128;
constexpr int K_    = 3;
constexpr int TFC_  = K_ * MID_;   // 768
constexpr int CTOT_ = MID_ + CORIG_; // 384

// -------------------------------------------------------------------------
// Kernel 1: temporal 1x1 conv -> tf[b][l2][o][n2], o in [0,768)
// C = Wt (768x512) x features[b,l2] (512x512)
// 128x64 block tile, 8x4 micro-tile. 32 acc regs (round-1's 64 ballooned
// VGPR to 148 -> occupancy cliff). As padded to 132 (round-0's unpadded
// As[16][64] write was a 16-way bank conflict: j*64 % 32 == 0).
// Accumulation order per output element: sequential K ascending fp32 FMA —
// bit-identical to previous versions.
// -------------------------------------------------------------------------
__global__ __launch_bounds__(256, 4) void tconv_gemm(const float* __restrict__ feat,
                                                     const float* __restrict__ Wt,
                                                     float* __restrict__ tf)
{
    __shared__ float As[16][132];  // As[j][i] = Wt[o0+i][kk+j], i in [0,128)
    __shared__ float Bs[16][68];   // Bs[j][i] = feat[kk+j][n0+i], i in [0,64)
    const int tid = threadIdx.x;
    const int n0 = blockIdx.x * 64;
    const int o0 = blockIdx.y * 128;
    const int batch = blockIdx.z;          // b*L2 + l2
    const float* Bp = feat + (size_t)batch * CIN_ * N2_;
    float acc[8][4] = {};
    const int tx = tid & 15, ty = tid >> 4;
    for (int kk = 0; kk < CIN_; kk += 16) {
        #pragma unroll
        for (int r = 0; r < 8; r++) {
            int e = tid + r * 256;
            int i = e >> 4, j = e & 15;    // 16 consecutive lanes read 16 contiguous Wt floats
            As[j][i] = Wt[(size_t)(o0 + i) * CIN_ + kk + j];
        }
        #pragma unroll
        for (int r = 0; r < 4; r++) {
            int e = tid + r * 256;
            int j = e >> 6, i = e & 63;    // wave writes one full Bs row: conflict-free
            Bs[j][i] = Bp[(size_t)(kk + j) * N2_ + n0 + i];
        }
        __syncthreads();
        #pragma unroll
        for (int j = 0; j < 16; j++) {
            float a[8], bb[4];
            #pragma unroll
            for (int r = 0; r < 8; r++) a[r] = As[j][ty * 8 + r];
            #pragma unroll
            for (int c = 0; c < 4; c++) bb[c] = Bs[j][tx * 4 + c];
            #pragma unroll
            for (int r = 0; r < 8; r++)
                #pragma unroll
                for (int c = 0; c < 4; c++)
                    acc[r][c] += a[r] * bb[c];
        }
        __syncthreads();
    }
    float* Cp = tf + (size_t)batch * TFC_ * N2_;
    #pragma unroll
    for (int r = 0; r < 8; r++) {
        int o = o0 + ty * 8 + r;
        float4 v = make_float4(acc[r][0], acc[r][1], acc[r][2], acc[r][3]);
        *(float4*)&Cp[(size_t)o * N2_ + n0 + tx * 4] = v;
    }
}

// -------------------------------------------------------------------------
// Kernel 2: BN statistics per channel-slice ch = l2*768 + o (2304 blocks)
// -------------------------------------------------------------------------
__global__ __launch_bounds__(256) void bn_stats(const float* __restrict__ tf,
                                                const float* __restrict__ gamma,
                                                const float* __restrict__ beta,
                                                float* __restrict__ scale,
                                                float* __restrict__ shift)
{
    const int ch = blockIdx.x;          // l2*TFC_ + o
    const int l2 = ch / TFC_;
    const int o  = ch % TFC_;
    const int mid = o % MID_;           // channel index within MID for gamma/beta
    const int tid = threadIdx.x;
    float s = 0.f, sq = 0.f;
    #pragma unroll
    for (int t = 0; t < 16; t++) {
        int v = tid + t * 256;          // 0..4095
        int b = v >> 9, n2 = v & 511;
        float x = tf[((size_t)(b * L2_ + l2) * TFC_ + o) * N2_ + n2];
        s += x; sq += x * x;
    }
    __shared__ float ss[256], sqs[256];
    ss[tid] = s; sqs[tid] = sq;
    __syncthreads();
    for (int st = 128; st > 0; st >>= 1) {
        if (tid < st) { ss[tid] += ss[tid + st]; sqs[tid] += sqs[tid + st]; }
        __syncthreads();
    }
    if (tid == 0) {
        float mean = ss[0] * (1.f / 4096.f);
        float var = fmaxf(sqs[0] * (1.f / 4096.f) - mean * mean, 0.f);
        float sc = gamma[mid] * rsqrtf(var + 1e-5f);
        scale[ch] = sc;
        shift[ch] = beta[mid] - mean * sc;
    }
}

// -------------------------------------------------------------------------
// Kernel 3: apply BN + ReLU in place on tf (9437184 elements)
// -------------------------------------------------------------------------
__global__ __launch_bounds__(256) void bn_apply(float* __restrict__ tf,
                                                const float* __restrict__ scale,
                                                const float* __restrict__ shift)
{
    int idx = blockIdx.x * 256 + threadIdx.x;
    int ch = (idx >> 9) % (L2_ * TFC_);
    float x = tf[idx];
    tf[idx] = fmaxf(x * scale[ch] + shift[ch], 0.f);
}

// -------------------------------------------------------------------------
// Kernel 4: 3-NN search + weights.
// Replicates the XLA:CPU fp32 arithmetic of the reference:
//   d2 = (|a|^2 + |n|^2) - 2*dot,  dot via Eigen-style ASCENDING FMA CHAIN
//   dot = fma(az*nz, fma(ay*ny, rn(ax*nx)))   <- the one free rounding choice
// norms/reduce and elementwise combine are separate per-op-rounded fp32 (HLO
// semantics). Only the top-3 SET matters (weighted sum is order-invariant),
// and the set is decided by these exact roundings at the 3rd/4th boundary.
// History: exact f64 selection -> absmax 0.566; no-FMA expanded -> 0.651.
// -------------------------------------------------------------------------
__global__ __launch_bounds__(256) void three_nn_kernel(const float* __restrict__ xyzs,
                                                       const float* __restrict__ oxyzs,
                                                       int* __restrict__ fbbuf,
                                                       float* __restrict__ wbuf)
{
    // temporal transpose gather table (t1 0-based)
    const int nsegs[7]  = {1, 1, 2, 1, 2, 1, 1};
    const int t2s[7][2] = {{0,0},{0,0},{0,1},{1,1},{1,2},{2,2},{2,2}};
    const int kks[7][2] = {{0,0},{1,1},{2,0},{1,1},{2,0},{1,1},{2,2}};

    const int tid = threadIdx.x;
    const int t1 = blockIdx.y;
    const int b  = blockIdx.z;
    const int M = nsegs[t1] * N2_;

    __shared__ float sx[1024], sy[1024], sz[1024], sn2[1024];
    for (int j = tid; j < M; j += 256) {
        int seg = j >> 9;
        int t2 = t2s[t1][seg];
        const float* p = xyzs + ((size_t)(b * L2_ + t2) * N2_ + (j & 511)) * 3;
        float x = p[0], y = p[1], z = p[2];
        sx[j] = x; sy[j] = y; sz[j] = z;
        // |n|^2 = ((x*x + y*y) + z*z), each op rounded fp32, no FMA (XLA reduce)
        sn2[j] = __fadd_rn(__fadd_rn(__fmul_rn(x, x), __fmul_rn(y, y)),
                           __fmul_rn(z, z));
    }
    __syncthreads();

    const int n1 = blockIdx.x * 256 + tid;
    const float* a = oxyzs + ((size_t)(b * L1_ + t1) * N1_ + n1) * 3;
    const float ax = a[0], ay = a[1], az = a[2];
    const float an2 = __fadd_rn(__fadd_rn(__fmul_rn(ax, ax), __fmul_rn(ay, ay)),
                                __fmul_rn(az, az));

    float d0 = 1e30f, d1 = 1e30f, d2v = 1e30f;
    int i0 = 0, i1 = 0, i2 = 0;
    for (int j = 0; j < M; j++) {
        // Eigen gemm K-loop: acc=0; acc=fma(a_k,b_k,acc) ascending ->
        // dot = rn(az*nz + rn(ay*ny + rn(ax*nx)))
        float dot = fmaf(az, sz[j], fmaf(ay, sy[j], __fmul_rn(ax, sx[j])));
        // d2 = (an2 + nn2) - rn(2*dot), separate HLO roundings
        float d = __fsub_rn(__fadd_rn(an2, sn2[j]), __fmul_rn(2.0f, dot));
        // stable ascending insertion (ties keep lower index) == top_k(-d2,3)
        if (d < d0)       { d2v = d1; i2 = i1; d1 = d0; i1 = i0; d0 = d; i0 = j; }
        else if (d < d1)  { d2v = d1; i2 = i1; d1 = d;  i1 = j; }
        else if (d < d2v) { d2v = d;  i2 = j; }
    }
    // dist = sqrt(max(d2, 1e-12)); w = 1/(dist + 1e-8); w /= sum(w)  — fp32
    float dist0 = sqrtf(fmaxf(d0,  1e-12f));
    float dist1 = sqrtf(fmaxf(d1,  1e-12f));
    float dist2 = sqrtf(fmaxf(d2v, 1e-12f));
    float w0 = 1.0f / __fadd_rn(dist0, 1e-8f);
    float w1 = 1.0f / __fadd_rn(dist1, 1e-8f);
    float w2 = 1.0f / __fadd_rn(dist2, 1e-8f);
    float wsum = __fadd_rn(__fadd_rn(w0, w1), w2);
    w0 = w0 / wsum; w1 = w1 / wsum; w2 = w2 / wsum;

    size_t base = ((size_t)(b * L1_ + t1) * N1_ + n1) * 3;
    int   idxs[3] = {i0, i1, i2};
    float wws[3]  = {w0, w1, w2};
    #pragma unroll
    for (int j = 0; j < 3; j++) {
        int seg = idxs[j] >> 9;
        int t2 = t2s[t1][seg];
        int k  = kks[t1][seg];
        fbbuf[base + j] = ((b * L2_ + t2) * K_ + k) * (MID_ * N2_) + (idxs[j] & 511);
        wbuf[base + j]  = wws[j];
    }
}

// -------------------------------------------------------------------------
// Kernel 5: spatial 1x1 conv with fused 3-NN gather + concat.
// Per (b,t1): C(512x2048) = Ws(512x384) x nf(384x2048),
// nf rows 0..255 gathered from sf via (fb, w), rows 256..383 from orig feats.
// 128x64 block tile, 8x4 micro-tile: 32 acc regs (occupancy-safe), gather
// redundancy 4x (OUT/128 o-blocks per n-tile), padded As (write-conflict fix).
// Per-output accumulation chain identical to previous versions (bit-exact).
// -------------------------------------------------------------------------
__global__ __launch_bounds__(256, 4) void sconv_gemm(const float* __restrict__ sf,
                                                     const float* __restrict__ of,
                                                     const float* __restrict__ Ws,
                                                     const int* __restrict__ fbbuf,
                                                     const float* __restrict__ wbuf,
                                                     float* __restrict__ outp)
{
    __shared__ float As[16][132];  // i in [0,128)
    __shared__ float Bs[16][68];   // i in [0,64)
    __shared__ int   sFB[192];
    __shared__ float sW[192];
    const int tid = threadIdx.x;
    const int n0 = blockIdx.x * 64;
    const int o0 = blockIdx.y * 128;
    const int bt = blockIdx.z;             // b*L1 + t1

    if (tid < 192) {
        size_t gbase = ((size_t)bt * N1_ + n0) * 3;
        sFB[tid] = fbbuf[gbase + tid];
        sW[tid]  = wbuf [gbase + tid];
    }
    __syncthreads();

    float acc[8][4] = {};
    const int tx = tid & 15, ty = tid >> 4;
    const float* ofp = of + (size_t)bt * CORIG_ * N1_;

    for (int kk = 0; kk < CTOT_; kk += 16) {
        #pragma unroll
        for (int r = 0; r < 8; r++) {
            int e = tid + r * 256;
            int i = e >> 4, j = e & 15;
            As[j][i] = Ws[(size_t)(o0 + i) * CTOT_ + kk + j];
        }
        #pragma unroll
        for (int r = 0; r < 4; r++) {
            int e = tid + r * 256;
            int j = e >> 6, i = e & 63;
            int c = kk + j;                // branch uniform per kk step (MID_%16==0)
            float v;
            if (c < MID_) {
                int gb = i * 3;
                size_t co = (size_t)c * N2_;
                v = sW[gb]     * sf[(size_t)sFB[gb]     + co]
                  + sW[gb + 1] * sf[(size_t)sFB[gb + 1] + co]
                  + sW[gb + 2] * sf[(size_t)sFB[gb + 2] + co];
            } else {
                v = ofp[(size_t)(c - MID_) * N1_ + n0 + i];
            }
            Bs[j][i] = v;
        }
        __syncthreads();
        #pragma unroll
        for (int j = 0; j < 16; j++) {
            float a[8], bb[4];
            #pragma unroll
            for (int r = 0; r < 8; r++) a[r] = As[j][ty * 8 + r];
            #pragma unroll
            for (int c = 0; c < 4; c++) bb[c] = Bs[j][tx * 4 + c];
            #pragma unroll
            for (int r = 0; r < 8; r++)
                #pragma unroll
                for (int c = 0; c < 4; c++)
                    acc[r][c] += a[r] * bb[c];
        }
        __syncthreads();
    }
    float* Cp = outp + (size_t)bt * OUT_ * N1_;
    #pragma unroll
    for (int r = 0; r < 8; r++) {
        int o = o0 + ty * 8 + r;
        float4 v = make_float4(acc[r][0], acc[r][1], acc[r][2], acc[r][3]);
        *(float4*)&Cp[(size_t)o * N1_ + n0 + tx * 4] = v;
    }
}

// -------------------------------------------------------------------------
extern "C" void kernel_launch(void* const* d_in, const int* in_sizes, int n_in,
                              void* d_out, int out_size, void* d_ws, size_t ws_size,
                              hipStream_t stream)
{
    const float* xyzs  = (const float*)d_in[0];  // (B, L2, N2, 3)
    const float* oxyzs = (const float*)d_in[1];  // (B, L1, N1, 3)
    const float* feats = (const float*)d_in[2];  // (B, L2, CIN, N2)
    const float* ofeat = (const float*)d_in[3];  // (B, L1, CORIG, N1)
    const float* Wt    = (const float*)d_in[4];  // (768, 512)
    const float* gamma = (const float*)d_in[5];  // (256,)
    const float* beta  = (const float*)d_in[6];  // (256,)
    const float* Ws    = (const float*)d_in[7];  // (512, 384)
    float* out = (float*)d_out;

    // workspace layout
    char* ws = (char*)d_ws;
    float* tf    = (float*)ws;                                   // 9437184 f = 37748736 B
    float* scale = (float*)(ws + 37748736);                      // 2304 f
    float* shift = scale + 2304;                                 // 2304 f
    int*   fbbuf = (int*)(ws + 37748736 + 18432);                // 344064 i
    float* wbuf  = (float*)(ws + 37748736 + 18432 + 1376256);    // 344064 f

    // Output 0: original_xyzs passthrough
    hipMemcpyAsync(out, oxyzs, (size_t)B_ * L1_ * N1_ * 3 * sizeof(float),
                   hipMemcpyDeviceToDevice, stream);
    float* out_nf = out + (size_t)B_ * L1_ * N1_ * 3;

    tconv_gemm<<<dim3(N2_ / 64, TFC_ / 128, B_ * L2_), 256, 0, stream>>>(feats, Wt, tf);
    bn_stats<<<L2_ * TFC_, 256, 0, stream>>>(tf, gamma, beta, scale, shift);
    bn_apply<<<(B_ * L2_ * TFC_ * N2_) / 256, 256, 0, stream>>>(tf, scale, shift);
    three_nn_kernel<<<dim3(N1_ / 256, L1_, B_), 256, 0, stream>>>(xyzs, oxyzs, fbbuf, wbuf);
    sconv_gemm<<<dim3(N1_ / 64, OUT_ / 128, B_ * L1_), 256, 0, stream>>>(tf, ofeat, Ws, fbbuf, wbuf, out_nf);
}

// Round 3
// 1106.736 us; speedup vs baseline: 1.9766x; 1.4532x over previous
//
#include <hip/hip_runtime.h>
#include <hip/hip_bf16.h>

// ---- static problem config ----
constexpr int B_    = 8;
constexpr int L1_   = 7;
constexpr int L2_   = 3;
constexpr int N1_   = 2048;
constexpr int N2_   = 512;
constexpr int CIN_  = 512;
constexpr int MID_  = 256;
constexpr int OUT_  = 512;
constexpr int CORIG_= 128;
constexpr int K_    = 3;
constexpr int TFC_  = K_ * MID_;     // 768
constexpr int CTOT_ = MID_ + CORIG_; // 384

// tf is stored TRANSPOSED: tf_t[b][l2][k][n2][mid]  (mid contiguous).
// Rationale (R3): gathered points' channels become contiguous -> float4
// gather loads in sconv (was 4B scattered scalars = latency/request bound,
// VALUBusy 38% with FMA floor 287us vs measured 1131us).

// -------------------------------------------------------------------------
// Kernel 1: temporal 1x1 conv -> tf_t, 128x64 tile, 8x4 micro-tile.
// Accumulation order per output element: sequential K ascending fp32 FMA —
// bit-identical to previous versions (only the store layout changed).
// XCD swizzle: 48 blocks per batch-slice pinned to one XCD.
// -------------------------------------------------------------------------
__global__ __launch_bounds__(256, 4) void tconv_gemm(const float* __restrict__ feat,
                                                     const float* __restrict__ Wt,
                                                     float* __restrict__ tf)
{
    __shared__ float As[16][132];  // As[j][i] = Wt[o0+i][kk+j], i in [0,128)
    __shared__ float Bs[16][68];   // Bs[j][i] = feat[kk+j][n0+i], i in [0,64)
    const int tid = threadIdx.x;
    // XCD-pinning swizzle: grid 1152 = 8 XCDs x 144; 48 blocks per batch.
    const int bid = blockIdx.x;
    const int logical = (bid & 7) * 144 + (bid >> 3);
    const int batch = logical / 48;        // b*L2 + l2, 0..23
    const int rr = logical % 48;
    const int o0 = (rr >> 3) * 128;        // 6 o-blocks
    const int n0 = (rr & 7) * 64;          // 8 n-tiles
    const float* Bp = feat + (size_t)batch * CIN_ * N2_;
    float acc[8][4] = {};
    const int tx = tid & 15, ty = tid >> 4;
    for (int kk = 0; kk < CIN_; kk += 16) {
        #pragma unroll
        for (int r = 0; r < 2; r++) {
            int e = tid + r * 256;         // 0..511
            int i = e >> 2, j4 = (e & 3) * 4;
            float4 w = *(const float4*)&Wt[(size_t)(o0 + i) * CIN_ + kk + j4];
            As[j4 + 0][i] = w.x; As[j4 + 1][i] = w.y;
            As[j4 + 2][i] = w.z; As[j4 + 3][i] = w.w;
        }
        {
            int j = tid >> 4, i4 = (tid & 15) * 4;
            float4 v = *(const float4*)&Bp[(size_t)(kk + j) * N2_ + n0 + i4];
            *(float4*)&Bs[j][i4] = v;
        }
        __syncthreads();
        #pragma unroll
        for (int j = 0; j < 16; j++) {
            float a[8], bb[4];
            #pragma unroll
            for (int r = 0; r < 8; r++) a[r] = As[j][ty * 8 + r];
            #pragma unroll
            for (int c = 0; c < 4; c++) bb[c] = Bs[j][tx * 4 + c];
            #pragma unroll
            for (int r = 0; r < 8; r++)
                #pragma unroll
                for (int c = 0; c < 4; c++)
                    acc[r][c] += a[r] * bb[c];
        }
        __syncthreads();
    }
    // transposed store: tf_t[batch][k][n2][mid]
    float* Cp = tf + (size_t)batch * TFC_ * N2_;   // TFC*N2 == K*N2*MID
    const int kseg = o0 >> 8;                      // o-block entirely within one k (128 | 256)
    const int mid0 = (o0 & 255) + ty * 8;
    #pragma unroll
    for (int c = 0; c < 4; c++) {
        int n2 = n0 + tx * 4 + c;
        float* dst = Cp + ((size_t)kseg * N2_ + n2) * MID_ + mid0;
        *(float4*)dst       = make_float4(acc[0][c], acc[1][c], acc[2][c], acc[3][c]);
        *(float4*)(dst + 4) = make_float4(acc[4][c], acc[5][c], acc[6][c], acc[7][c]);
    }
}

// -------------------------------------------------------------------------
// Kernel 2a: BN partial sums over tf_t. grid (64 row-chunks, 9 (l2,k) groups).
// Lane = mid -> fully coalesced 1KB row reads. Deterministic partials.
// -------------------------------------------------------------------------
__global__ __launch_bounds__(256) void bn_stats1(const float* __restrict__ tf,
                                                 float* __restrict__ ps,
                                                 float* __restrict__ pq)
{
    const int g  = blockIdx.y;        // l2*3 + k
    const int rc = blockIdx.x;        // 64-row chunk of the 4096 (b,n2) rows
    const int mid = threadIdx.x;
    float s = 0.f, sq = 0.f;
    for (int r = 0; r < 64; r++) {
        int row = rc * 64 + r;        // row = b*512 + n2
        int b = row >> 9, n2 = row & 511;
        float x = tf[((size_t)(b * 9 + g) * N2_ + n2) * MID_ + mid];
        s += x; sq += x * x;
    }
    ps[(g * 64 + rc) * 256 + mid] = s;
    pq[(g * 64 + rc) * 256 + mid] = sq;
}

// -------------------------------------------------------------------------
// Kernel 2b: finalize BN scale/shift. 2304 channels, ch = g*256 + mid
// (== l2*768 + k*256 + mid, same ordering as before).
// -------------------------------------------------------------------------
__global__ __launch_bounds__(256) void bn_stats2(const float* __restrict__ ps,
                                                 const float* __restrict__ pq,
                                                 const float* __restrict__ gamma,
                                                 const float* __restrict__ beta,
                                                 float* __restrict__ scale,
                                                 float* __restrict__ shift)
{
    const int ch = blockIdx.x * 256 + threadIdx.x;
    const int g = ch >> 8, mid = ch & 255;
    float s = 0.f, sq = 0.f;
    for (int r = 0; r < 64; r++) {
        s  += ps[(g * 64 + r) * 256 + mid];
        sq += pq[(g * 64 + r) * 256 + mid];
    }
    float mean = s * (1.f / 4096.f);
    float var = fmaxf(sq * (1.f / 4096.f) - mean * mean, 0.f);
    float sc = gamma[mid] * rsqrtf(var + 1e-5f);
    scale[ch] = sc;
    shift[ch] = beta[mid] - mean * sc;
}

// -------------------------------------------------------------------------
// Kernel 3: apply BN + ReLU in place on tf_t (float4 vectorized).
// -------------------------------------------------------------------------
__global__ __launch_bounds__(256) void bn_apply(float* __restrict__ tf,
                                                const float* __restrict__ scale,
                                                const float* __restrict__ shift)
{
    int idx = (blockIdx.x * 256 + threadIdx.x) * 4;
    int mid = idx & 255;
    int g = (idx >> 17) % 9;          // idx / (N2*MID) % 9
    int ch = g * 256 + mid;
    float4 x = *(float4*)&tf[idx];
    x.x = fmaxf(x.x * scale[ch]     + shift[ch],     0.f);
    x.y = fmaxf(x.y * scale[ch + 1] + shift[ch + 1], 0.f);
    x.z = fmaxf(x.z * scale[ch + 2] + shift[ch + 2], 0.f);
    x.w = fmaxf(x.w * scale[ch + 3] + shift[ch + 3], 0.f);
    *(float4*)&tf[idx] = x;
}

// -------------------------------------------------------------------------
// Kernel 4: 3-NN search + weights.
// Replicates the XLA:CPU fp32 arithmetic of the reference:
//   d2 = (|a|^2 + |n|^2) - 2*dot,  dot via Eigen-style ASCENDING FMA CHAIN
//   dot = fma(az*nz, fma(ay*ny, rn(ax*nx)))   <- the one free rounding choice
// Selection arithmetic UNchanged from the accepted kernel (absmax 0.0156).
// Only the emitted fbbuf base changed: points into tf_t (n2*MID, mid-contig).
// -------------------------------------------------------------------------
__global__ __launch_bounds__(256) void three_nn_kernel(const float* __restrict__ xyzs,
                                                       const float* __restrict__ oxyzs,
                                                       int* __restrict__ fbbuf,
                                                       float* __restrict__ wbuf)
{
    // temporal transpose gather table (t1 0-based)
    const int nsegs[7]  = {1, 1, 2, 1, 2, 1, 1};
    const int t2s[7][2] = {{0,0},{0,0},{0,1},{1,1},{1,2},{2,2},{2,2}};
    const int kks[7][2] = {{0,0},{1,1},{2,0},{1,1},{2,0},{1,1},{2,2}};

    const int tid = threadIdx.x;
    const int t1 = blockIdx.y;
    const int b  = blockIdx.z;
    const int M = nsegs[t1] * N2_;

    __shared__ float sx[1024], sy[1024], sz[1024], sn2[1024];
    for (int j = tid; j < M; j += 256) {
        int seg = j >> 9;
        int t2 = t2s[t1][seg];
        const float* p = xyzs + ((size_t)(b * L2_ + t2) * N2_ + (j & 511)) * 3;
        float x = p[0], y = p[1], z = p[2];
        sx[j] = x; sy[j] = y; sz[j] = z;
        sn2[j] = __fadd_rn(__fadd_rn(__fmul_rn(x, x), __fmul_rn(y, y)),
                           __fmul_rn(z, z));
    }
    __syncthreads();

    const int n1 = blockIdx.x * 256 + tid;
    const float* a = oxyzs + ((size_t)(b * L1_ + t1) * N1_ + n1) * 3;
    const float ax = a[0], ay = a[1], az = a[2];
    const float an2 = __fadd_rn(__fadd_rn(__fmul_rn(ax, ax), __fmul_rn(ay, ay)),
                                __fmul_rn(az, az));

    float d0 = 1e30f, d1 = 1e30f, d2v = 1e30f;
    int i0 = 0, i1 = 0, i2 = 0;
    for (int j = 0; j < M; j++) {
        float dot = fmaf(az, sz[j], fmaf(ay, sy[j], __fmul_rn(ax, sx[j])));
        float d = __fsub_rn(__fadd_rn(an2, sn2[j]), __fmul_rn(2.0f, dot));
        if (d < d0)       { d2v = d1; i2 = i1; d1 = d0; i1 = i0; d0 = d; i0 = j; }
        else if (d < d1)  { d2v = d1; i2 = i1; d1 = d;  i1 = j; }
        else if (d < d2v) { d2v = d;  i2 = j; }
    }
    float dist0 = sqrtf(fmaxf(d0,  1e-12f));
    float dist1 = sqrtf(fmaxf(d1,  1e-12f));
    float dist2 = sqrtf(fmaxf(d2v, 1e-12f));
    float w0 = 1.0f / __fadd_rn(dist0, 1e-8f);
    float w1 = 1.0f / __fadd_rn(dist1, 1e-8f);
    float w2 = 1.0f / __fadd_rn(dist2, 1e-8f);
    float wsum = __fadd_rn(__fadd_rn(w0, w1), w2);
    w0 = w0 / wsum; w1 = w1 / wsum; w2 = w2 / wsum;

    size_t base = ((size_t)(b * L1_ + t1) * N1_ + n1) * 3;
    int   idxs[3] = {i0, i1, i2};
    float wws[3]  = {w0, w1, w2};
    #pragma unroll
    for (int j = 0; j < 3; j++) {
        int seg = idxs[j] >> 9;
        int t2 = t2s[t1][seg];
        int k  = kks[t1][seg];
        // base offset into tf_t: channels are contiguous at +mid
        fbbuf[base + j] = ((b * L2_ + t2) * K_ + k) * (MID_ * N2_)
                        + (idxs[j] & 511) * MID_;
        wbuf[base + j]  = wws[j];
    }
}

// -------------------------------------------------------------------------
// Kernel 5: spatial 1x1 conv with fused 3-NN gather + concat.
// Per (b,t1): C(512x2048) = Ws(512x384) x nf(384x2048).
// Gather now reads tf_t with float4 channel loads (3 x 16B per thread per
// kk-step instead of 12 scattered 4B scalars). XCD swizzle pins all 128
// blocks of one bt-slice (~2MB working set) to one XCD L2 (was 8x
// re-fetch: FETCH 432MB ~= 56 slices x 1MB x 8 XCDs).
// Per-output accumulation chain identical to previous versions.
// -------------------------------------------------------------------------
__global__ __launch_bounds__(256, 4) void sconv_gemm(const float* __restrict__ sf,
                                                     const float* __restrict__ of,
                                                     const float* __restrict__ Ws,
                                                     const int* __restrict__ fbbuf,
                                                     const float* __restrict__ wbuf,
                                                     float* __restrict__ outp)
{
    __shared__ float As[16][132];  // i in [0,128)
    __shared__ float Bs[16][68];   // i in [0,64)
    __shared__ int   sFB[192];
    __shared__ float sW[192];
    const int tid = threadIdx.x;
    // XCD-pinning swizzle: grid 7168 = 8 XCDs x 896; 128 blocks per bt.
    const int bid = blockIdx.x;
    const int logical = (bid & 7) * 896 + (bid >> 3);
    const int bt = logical / 128;          // b*L1 + t1, 0..55
    const int rr = logical % 128;
    const int o0 = (rr >> 5) * 128;        // 4 o-blocks
    const int n0 = (rr & 31) * 64;         // 32 n-tiles

    if (tid < 192) {
        size_t gbase = ((size_t)bt * N1_ + n0) * 3;
        sFB[tid] = fbbuf[gbase + tid];
        sW[tid]  = wbuf [gbase + tid];
    }
    __syncthreads();

    float acc[8][4] = {};
    const int tx = tid & 15, ty = tid >> 4;
    const float* ofp = of + (size_t)bt * CORIG_ * N1_;

    for (int kk = 0; kk < CTOT_; kk += 16) {
        #pragma unroll
        for (int r = 0; r < 2; r++) {
            int e = tid + r * 256;         // 0..511
            int i = e >> 2, j4 = (e & 3) * 4;
            float4 w = *(const float4*)&Ws[(size_t)(o0 + i) * CTOT_ + kk + j4];
            As[j4 + 0][i] = w.x; As[j4 + 1][i] = w.y;
            As[j4 + 2][i] = w.z; As[j4 + 3][i] = w.w;
        }
        if (kk < MID_) {
            // gather: thread = (point i, channel-group cg); 3 float4 loads
            int i = tid & 63, cg = tid >> 6;
            int c = kk + cg * 4;
            int gb = i * 3;
            const float4 v0 = *(const float4*)&sf[(size_t)sFB[gb]     + c];
            const float4 v1 = *(const float4*)&sf[(size_t)sFB[gb + 1] + c];
            const float4 v2 = *(const float4*)&sf[(size_t)sFB[gb + 2] + c];
            float w0 = sW[gb], w1 = sW[gb + 1], w2 = sW[gb + 2];
            Bs[cg * 4 + 0][i] = w0 * v0.x + w1 * v1.x + w2 * v2.x;
            Bs[cg * 4 + 1][i] = w0 * v0.y + w1 * v1.y + w2 * v2.y;
            Bs[cg * 4 + 2][i] = w0 * v0.z + w1 * v1.z + w2 * v2.z;
            Bs[cg * 4 + 3][i] = w0 * v0.w + w1 * v1.w + w2 * v2.w;
        } else {
            int j = tid >> 4, i4 = (tid & 15) * 4;
            int c = kk + j;
            float4 v = *(const float4*)&ofp[(size_t)(c - MID_) * N1_ + n0 + i4];
            *(float4*)&Bs[j][i4] = v;
        }
        __syncthreads();
        #pragma unroll
        for (int j = 0; j < 16; j++) {
            float a[8], bb[4];
            #pragma unroll
            for (int r = 0; r < 8; r++) a[r] = As[j][ty * 8 + r];
            #pragma unroll
            for (int c = 0; c < 4; c++) bb[c] = Bs[j][tx * 4 + c];
            #pragma unroll
            for (int r = 0; r < 8; r++)
                #pragma unroll
                for (int c = 0; c < 4; c++)
                    acc[r][c] += a[r] * bb[c];
        }
        __syncthreads();
    }
    float* Cp = outp + (size_t)bt * OUT_ * N1_;
    #pragma unroll
    for (int r = 0; r < 8; r++) {
        int o = o0 + ty * 8 + r;
        float4 v = make_float4(acc[r][0], acc[r][1], acc[r][2], acc[r][3]);
        *(float4*)&Cp[(size_t)o * N1_ + n0 + tx * 4] = v;
    }
}

// -------------------------------------------------------------------------
extern "C" void kernel_launch(void* const* d_in, const int* in_sizes, int n_in,
                              void* d_out, int out_size, void* d_ws, size_t ws_size,
                              hipStream_t stream)
{
    const float* xyzs  = (const float*)d_in[0];  // (B, L2, N2, 3)
    const float* oxyzs = (const float*)d_in[1];  // (B, L1, N1, 3)
    const float* feats = (const float*)d_in[2];  // (B, L2, CIN, N2)
    const float* ofeat = (const float*)d_in[3];  // (B, L1, CORIG, N1)
    const float* Wt    = (const float*)d_in[4];  // (768, 512)
    const float* gamma = (const float*)d_in[5];  // (256,)
    const float* beta  = (const float*)d_in[6];  // (256,)
    const float* Ws    = (const float*)d_in[7];  // (512, 384)
    float* out = (float*)d_out;

    // workspace layout
    char* ws = (char*)d_ws;
    float* tf    = (float*)ws;                                   // 37748736 B (transposed layout)
    float* scale = (float*)(ws + 37748736);                      // 2304 f
    float* shift = scale + 2304;                                 // 2304 f
    int*   fbbuf = (int*)(ws + 37748736 + 18432);                // 344064 i
    float* wbuf  = (float*)(ws + 37748736 + 18432 + 1376256);    // 344064 f
    float* ps    = (float*)(ws + 37748736 + 18432 + 2752512);    // 147456 f
    float* pq    = ps + 147456;                                  // 147456 f

    // Output 0: original_xyzs passthrough
    hipMemcpyAsync(out, oxyzs, (size_t)B_ * L1_ * N1_ * 3 * sizeof(float),
                   hipMemcpyDeviceToDevice, stream);
    float* out_nf = out + (size_t)B_ * L1_ * N1_ * 3;

    tconv_gemm<<<1152, 256, 0, stream>>>(feats, Wt, tf);
    bn_stats1<<<dim3(64, 9), 256, 0, stream>>>(tf, ps, pq);
    bn_stats2<<<9, 256, 0, stream>>>(ps, pq, gamma, beta, scale, shift);
    bn_apply<<<(B_ * L2_ * TFC_ * N2_) / 1024, 256, 0, stream>>>(tf, scale, shift);
    three_nn_kernel<<<dim3(N1_ / 256, L1_, B_), 256, 0, stream>>>(xyzs, oxyzs, fbbuf, wbuf);
    sconv_gemm<<<7168, 256, 0, stream>>>(tf, ofeat, Ws, fbbuf, wbuf, out_nf);
}

// Round 4
// 774.429 us; speedup vs baseline: 2.8247x; 1.4291x over previous
//
#include <hip/hip_runtime.h>
#include <hip/hip_bf16.h>

// ---- static problem config ----
constexpr int B_    = 8;
constexpr int L1_   = 7;
constexpr int L2_   = 3;
constexpr int N1_   = 2048;
constexpr int N2_   = 512;
constexpr int CIN_  = 512;
constexpr int MID_  = 256;
constexpr int OUT_  = 512;
constexpr int CORIG_= 128;
constexpr int K_    = 3;
constexpr int TFC_  = K_ * MID_;     // 768
constexpr int CTOT_ = MID_ + CORIG_; // 384

typedef __attribute__((ext_vector_type(8))) short bf16x8;
typedef __attribute__((ext_vector_type(4))) float f32x4;

// fp32 -> bf16 round-to-nearest-even (finite values)
__device__ inline ushort f2bf(float x) {
    uint u = __float_as_uint(x);
    uint r = (u + 0x7fffu + ((u >> 16) & 1u)) >> 16;
    return (ushort)r;
}
__device__ inline float bf2f(ushort h) {
    return __uint_as_float(((uint)h) << 16);
}

// -------------------------------------------------------------------------
// Kernel 1: temporal 1x1 conv -> tf_t[b][l2][k][n2][mid], 128x64 tile,
// 8x4 micro-tile, fp32 vector FMA (unchanged from round 3, verified).
// -------------------------------------------------------------------------
__global__ __launch_bounds__(256, 4) void tconv_gemm(const float* __restrict__ feat,
                                                     const float* __restrict__ Wt,
                                                     float* __restrict__ tf)
{
    __shared__ float As[16][132];
    __shared__ float Bs[16][68];
    const int tid = threadIdx.x;
    const int bid = blockIdx.x;
    const int logical = (bid & 7) * 144 + (bid >> 3);
    const int batch = logical / 48;        // b*L2 + l2, 0..23
    const int rr = logical % 48;
    const int o0 = (rr >> 3) * 128;
    const int n0 = (rr & 7) * 64;
    const float* Bp = feat + (size_t)batch * CIN_ * N2_;
    float acc[8][4] = {};
    const int tx = tid & 15, ty = tid >> 4;
    for (int kk = 0; kk < CIN_; kk += 16) {
        #pragma unroll
        for (int r = 0; r < 2; r++) {
            int e = tid + r * 256;
            int i = e >> 2, j4 = (e & 3) * 4;
            float4 w = *(const float4*)&Wt[(size_t)(o0 + i) * CIN_ + kk + j4];
            As[j4 + 0][i] = w.x; As[j4 + 1][i] = w.y;
            As[j4 + 2][i] = w.z; As[j4 + 3][i] = w.w;
        }
        {
            int j = tid >> 4, i4 = (tid & 15) * 4;
            float4 v = *(const float4*)&Bp[(size_t)(kk + j) * N2_ + n0 + i4];
            *(float4*)&Bs[j][i4] = v;
        }
        __syncthreads();
        #pragma unroll
        for (int j = 0; j < 16; j++) {
            float a[8], bb[4];
            #pragma unroll
            for (int r = 0; r < 8; r++) a[r] = As[j][ty * 8 + r];
            #pragma unroll
            for (int c = 0; c < 4; c++) bb[c] = Bs[j][tx * 4 + c];
            #pragma unroll
            for (int r = 0; r < 8; r++)
                #pragma unroll
                for (int c = 0; c < 4; c++)
                    acc[r][c] += a[r] * bb[c];
        }
        __syncthreads();
    }
    float* Cp = tf + (size_t)batch * TFC_ * N2_;
    const int kseg = o0 >> 8;
    const int mid0 = (o0 & 255) + ty * 8;
    #pragma unroll
    for (int c = 0; c < 4; c++) {
        int n2 = n0 + tx * 4 + c;
        float* dst = Cp + ((size_t)kseg * N2_ + n2) * MID_ + mid0;
        *(float4*)dst       = make_float4(acc[0][c], acc[1][c], acc[2][c], acc[3][c]);
        *(float4*)(dst + 4) = make_float4(acc[4][c], acc[5][c], acc[6][c], acc[7][c]);
    }
}

// -------------------------------------------------------------------------
// Kernel 2a/2b: BN stats over tf_t (unchanged from round 3).
// -------------------------------------------------------------------------
__global__ __launch_bounds__(256) void bn_stats1(const float* __restrict__ tf,
                                                 float* __restrict__ ps,
                                                 float* __restrict__ pq)
{
    const int g  = blockIdx.y;
    const int rc = blockIdx.x;
    const int mid = threadIdx.x;
    float s = 0.f, sq = 0.f;
    for (int r = 0; r < 64; r++) {
        int row = rc * 64 + r;
        int b = row >> 9, n2 = row & 511;
        float x = tf[((size_t)(b * 9 + g) * N2_ + n2) * MID_ + mid];
        s += x; sq += x * x;
    }
    ps[(g * 64 + rc) * 256 + mid] = s;
    pq[(g * 64 + rc) * 256 + mid] = sq;
}

__global__ __launch_bounds__(256) void bn_stats2(const float* __restrict__ ps,
                                                 const float* __restrict__ pq,
                                                 const float* __restrict__ gamma,
                                                 const float* __restrict__ beta,
                                                 float* __restrict__ scale,
                                                 float* __restrict__ shift)
{
    const int ch = blockIdx.x * 256 + threadIdx.x;
    const int g = ch >> 8, mid = ch & 255;
    float s = 0.f, sq = 0.f;
    for (int r = 0; r < 64; r++) {
        s  += ps[(g * 64 + r) * 256 + mid];
        sq += pq[(g * 64 + r) * 256 + mid];
    }
    float mean = s * (1.f / 4096.f);
    float var = fmaxf(sq * (1.f / 4096.f) - mean * mean, 0.f);
    float sc = gamma[mid] * rsqrtf(var + 1e-5f);
    scale[ch] = sc;
    shift[ch] = beta[mid] - mean * sc;
}

// -------------------------------------------------------------------------
// Kernel 3: apply BN + ReLU in place on tf_t (unchanged from round 3).
// -------------------------------------------------------------------------
__global__ __launch_bounds__(256) void bn_apply(float* __restrict__ tf,
                                                const float* __restrict__ scale,
                                                const float* __restrict__ shift)
{
    int idx = (blockIdx.x * 256 + threadIdx.x) * 4;
    int mid = idx & 255;
    int g = (idx >> 17) % 9;
    int ch = g * 256 + mid;
    float4 x = *(float4*)&tf[idx];
    x.x = fmaxf(x.x * scale[ch]     + shift[ch],     0.f);
    x.y = fmaxf(x.y * scale[ch + 1] + shift[ch + 1], 0.f);
    x.z = fmaxf(x.z * scale[ch + 2] + shift[ch + 2], 0.f);
    x.w = fmaxf(x.w * scale[ch + 3] + shift[ch + 3], 0.f);
    *(float4*)&tf[idx] = x;
}

// -------------------------------------------------------------------------
// Kernel 4: 3-NN search + weights (selection arithmetic UNCHANGED — it is
// what pins absmax at 0.0156; coordinates never touch the GEMMs).
// -------------------------------------------------------------------------
__global__ __launch_bounds__(256) void three_nn_kernel(const float* __restrict__ xyzs,
                                                       const float* __restrict__ oxyzs,
                                                       int* __restrict__ fbbuf,
                                                       float* __restrict__ wbuf)
{
    const int nsegs[7]  = {1, 1, 2, 1, 2, 1, 1};
    const int t2s[7][2] = {{0,0},{0,0},{0,1},{1,1},{1,2},{2,2},{2,2}};
    const int kks[7][2] = {{0,0},{1,1},{2,0},{1,1},{2,0},{1,1},{2,2}};

    const int tid = threadIdx.x;
    const int t1 = blockIdx.y;
    const int b  = blockIdx.z;
    const int M = nsegs[t1] * N2_;

    __shared__ float sx[1024], sy[1024], sz[1024], sn2[1024];
    for (int j = tid; j < M; j += 256) {
        int seg = j >> 9;
        int t2 = t2s[t1][seg];
        const float* p = xyzs + ((size_t)(b * L2_ + t2) * N2_ + (j & 511)) * 3;
        float x = p[0], y = p[1], z = p[2];
        sx[j] = x; sy[j] = y; sz[j] = z;
        sn2[j] = __fadd_rn(__fadd_rn(__fmul_rn(x, x), __fmul_rn(y, y)),
                           __fmul_rn(z, z));
    }
    __syncthreads();

    const int n1 = blockIdx.x * 256 + tid;
    const float* a = oxyzs + ((size_t)(b * L1_ + t1) * N1_ + n1) * 3;
    const float ax = a[0], ay = a[1], az = a[2];
    const float an2 = __fadd_rn(__fadd_rn(__fmul_rn(ax, ax), __fmul_rn(ay, ay)),
                                __fmul_rn(az, az));

    float d0 = 1e30f, d1 = 1e30f, d2v = 1e30f;
    int i0 = 0, i1 = 0, i2 = 0;
    for (int j = 0; j < M; j++) {
        float dot = fmaf(az, sz[j], fmaf(ay, sy[j], __fmul_rn(ax, sx[j])));
        float d = __fsub_rn(__fadd_rn(an2, sn2[j]), __fmul_rn(2.0f, dot));
        if (d < d0)       { d2v = d1; i2 = i1; d1 = d0; i1 = i0; d0 = d; i0 = j; }
        else if (d < d1)  { d2v = d1; i2 = i1; d1 = d;  i1 = j; }
        else if (d < d2v) { d2v = d;  i2 = j; }
    }
    float dist0 = sqrtf(fmaxf(d0,  1e-12f));
    float dist1 = sqrtf(fmaxf(d1,  1e-12f));
    float dist2 = sqrtf(fmaxf(d2v, 1e-12f));
    float w0 = 1.0f / __fadd_rn(dist0, 1e-8f);
    float w1 = 1.0f / __fadd_rn(dist1, 1e-8f);
    float w2 = 1.0f / __fadd_rn(dist2, 1e-8f);
    float wsum = __fadd_rn(__fadd_rn(w0, w1), w2);
    w0 = w0 / wsum; w1 = w1 / wsum; w2 = w2 / wsum;

    size_t base = ((size_t)(b * L1_ + t1) * N1_ + n1) * 3;
    int   idxs[3] = {i0, i1, i2};
    float wws[3]  = {w0, w1, w2};
    #pragma unroll
    for (int j = 0; j < 3; j++) {
        int seg = idxs[j] >> 9;
        int t2 = t2s[t1][seg];
        int k  = kks[t1][seg];
        fbbuf[base + j] = ((b * L2_ + t2) * K_ + k) * (MID_ * N2_)
                        + (idxs[j] & 511) * MID_;
        wbuf[base + j]  = wws[j];
    }
}

// -------------------------------------------------------------------------
// Kernel 5: spatial 1x1 conv, split-bf16 MFMA emulation.
// Per (b,t1): C(512x2048) = Ws(512x384) x nf(384x2048).
// x = hi + lo (two bf16); a*b ~= ahi*bhi + alo*bhi + ahi*blo (3 MFMAs,
// fp32 accumulate). Dropped lo*lo + split rounding ~2^-17 rel -> <=1e-4
// abs on O(1) outputs, vs absmax 0.0156 from 3-NN selection.
// Tile 128x128, 4 waves (2x2), each wave 4x4 frags of 16x16x32 bf16 MFMA.
// LDS [row][k] bf16, row stride 40 ushorts (20 dwords: period-8 banks ->
// 2-way frag reads, free per m136). Staging quad-mapped (row=linear>>2,
// blk=linear&3) to spread write banks. Gather fp32 interp as round 3,
// split at LDS-write. C/D layout: col=lane&15, row=(lane>>4)*4+reg (m89).
// A/B layout: row/col=lane%16, k=8*(lane>>4)+elem (canonical).
// -------------------------------------------------------------------------
__global__ __launch_bounds__(256, 3) void sconv_mfma(const float* __restrict__ sf,
                                                     const float* __restrict__ of,
                                                     const float* __restrict__ Ws,
                                                     const int* __restrict__ fbbuf,
                                                     const float* __restrict__ wbuf,
                                                     float* __restrict__ outp)
{
    __shared__ ushort Ahi[128][40], Alo[128][40];   // Ws tile  [m][k]
    __shared__ ushort Bhi[128][40], Blo[128][40];   // nf tile  [n][k]
    __shared__ int   sFB[384];
    __shared__ float sW[384];

    const int tid = threadIdx.x;
    // XCD-pinning: grid 3584 = 8 XCDs x 448; 64 blocks per bt contiguous.
    const int bid = blockIdx.x;
    const int logical = (bid & 7) * 448 + (bid >> 3);
    const int bt = logical / 64;           // b*L1 + t1
    const int rr = logical % 64;
    const int o0 = (rr >> 4) * 128;        // 4 o-blocks
    const int n0 = (rr & 15) * 128;        // 16 n-tiles

    for (int t = tid; t < 384; t += 256) {
        size_t gbase = ((size_t)bt * N1_ + n0) * 3;
        sFB[t] = fbbuf[gbase + t];
        sW[t]  = wbuf [gbase + t];
    }

    const int lane = tid & 63;
    const int wv   = tid >> 6;             // 0..3
    const int wm   = wv >> 1, wn = wv & 1; // 2x2 wave grid, 64x64 per wave
    const int kb   = lane >> 4;            // k-block 0..3 (8 bf16 each)
    const int lr   = lane & 15;

    const float* ofp = of + (size_t)bt * CORIG_ * N1_;

    f32x4 acc[4][4];
    #pragma unroll
    for (int mi = 0; mi < 4; mi++)
        #pragma unroll
        for (int ni = 0; ni < 4; ni++)
            acc[mi][ni] = (f32x4){0.f, 0.f, 0.f, 0.f};

    for (int kk = 0; kk < CTOT_; kk += 32) {
        __syncthreads();                   // WAR: prior compute done reading
        // ---- stage A: Ws[o0+m][kk .. kk+32) -> Ahi/Alo[m][0..32) ----
        #pragma unroll
        for (int r = 0; r < 2; r++) {
            int linear = r * 256 + tid;
            int m = linear >> 2, blk = linear & 3;
            const float* src = Ws + (size_t)(o0 + m) * CTOT_ + kk + blk * 8;
            float4 x0 = *(const float4*)src;
            float4 x1 = *(const float4*)(src + 4);
            float v[8] = {x0.x, x0.y, x0.z, x0.w, x1.x, x1.y, x1.z, x1.w};
            uint hw[4], lw[4];
            #pragma unroll
            for (int p = 0; p < 4; p++) {
                ushort h0 = f2bf(v[2*p]),   h1 = f2bf(v[2*p+1]);
                ushort l0 = f2bf(v[2*p]   - bf2f(h0));
                ushort l1 = f2bf(v[2*p+1] - bf2f(h1));
                hw[p] = (uint)h0 | ((uint)h1 << 16);
                lw[p] = (uint)l0 | ((uint)l1 << 16);
            }
            *(uint4*)&Ahi[m][blk * 8] = make_uint4(hw[0], hw[1], hw[2], hw[3]);
            *(uint4*)&Alo[m][blk * 8] = make_uint4(lw[0], lw[1], lw[2], lw[3]);
        }
        // ---- stage B: nf rows kk..kk+32 for points n0..n0+128 ----
        #pragma unroll
        for (int r = 0; r < 2; r++) {
            int linear = r * 256 + tid;
            int i = linear >> 2, blk = linear & 3;
            float v[8];
            if (kk < MID_) {
                int gb = i * 3;
                int c = kk + blk * 8;
                const float w0 = sW[gb], w1 = sW[gb + 1], w2 = sW[gb + 2];
                const size_t f0 = (size_t)sFB[gb];
                const size_t f1 = (size_t)sFB[gb + 1];
                const size_t f2 = (size_t)sFB[gb + 2];
                #pragma unroll
                for (int q = 0; q < 2; q++) {
                    float4 a0 = *(const float4*)&sf[f0 + c + q * 4];
                    float4 a1 = *(const float4*)&sf[f1 + c + q * 4];
                    float4 a2 = *(const float4*)&sf[f2 + c + q * 4];
                    v[q*4+0] = w0 * a0.x + w1 * a1.x + w2 * a2.x;
                    v[q*4+1] = w0 * a0.y + w1 * a1.y + w2 * a2.y;
                    v[q*4+2] = w0 * a0.z + w1 * a1.z + w2 * a2.z;
                    v[q*4+3] = w0 * a0.w + w1 * a1.w + w2 * a2.w;
                }
            } else {
                int c = kk + blk * 8 - MID_;
                #pragma unroll
                for (int j = 0; j < 8; j++)
                    v[j] = ofp[(size_t)(c + j) * N1_ + n0 + i];
            }
            uint hw[4], lw[4];
            #pragma unroll
            for (int p = 0; p < 4; p++) {
                ushort h0 = f2bf(v[2*p]),   h1 = f2bf(v[2*p+1]);
                ushort l0 = f2bf(v[2*p]   - bf2f(h0));
                ushort l1 = f2bf(v[2*p+1] - bf2f(h1));
                hw[p] = (uint)h0 | ((uint)h1 << 16);
                lw[p] = (uint)l0 | ((uint)l1 << 16);
            }
            *(uint4*)&Bhi[i][blk * 8] = make_uint4(hw[0], hw[1], hw[2], hw[3]);
            *(uint4*)&Blo[i][blk * 8] = make_uint4(lw[0], lw[1], lw[2], lw[3]);
        }
        __syncthreads();
        // ---- compute: 4x4 frags x 3 MFMAs ----
        bf16x8 ah[4], al[4];
        #pragma unroll
        for (int mi = 0; mi < 4; mi++) {
            ah[mi] = *(const bf16x8*)&Ahi[wm * 64 + mi * 16 + lr][kb * 8];
            al[mi] = *(const bf16x8*)&Alo[wm * 64 + mi * 16 + lr][kb * 8];
        }
        #pragma unroll
        for (int ni = 0; ni < 4; ni++) {
            bf16x8 bh = *(const bf16x8*)&Bhi[wn * 64 + ni * 16 + lr][kb * 8];
            bf16x8 bl = *(const bf16x8*)&Blo[wn * 64 + ni * 16 + lr][kb * 8];
            #pragma unroll
            for (int mi = 0; mi < 4; mi++) {
                acc[mi][ni] = __builtin_amdgcn_mfma_f32_16x16x32_bf16(ah[mi], bh, acc[mi][ni], 0, 0, 0);
                acc[mi][ni] = __builtin_amdgcn_mfma_f32_16x16x32_bf16(al[mi], bh, acc[mi][ni], 0, 0, 0);
                acc[mi][ni] = __builtin_amdgcn_mfma_f32_16x16x32_bf16(ah[mi], bl, acc[mi][ni], 0, 0, 0);
            }
        }
    }
    // ---- epilogue: C/D layout col=lane&15, row=(lane>>4)*4+reg (m89) ----
    float* Cp = outp + (size_t)bt * OUT_ * N1_;
    #pragma unroll
    for (int mi = 0; mi < 4; mi++) {
        int row0 = o0 + wm * 64 + mi * 16 + (lane >> 4) * 4;
        #pragma unroll
        for (int ni = 0; ni < 4; ni++) {
            int col = n0 + wn * 64 + ni * 16 + lr;
            #pragma unroll
            for (int v = 0; v < 4; v++)
                Cp[(size_t)(row0 + v) * N1_ + col] = acc[mi][ni][v];
        }
    }
}

// -------------------------------------------------------------------------
extern "C" void kernel_launch(void* const* d_in, const int* in_sizes, int n_in,
                              void* d_out, int out_size, void* d_ws, size_t ws_size,
                              hipStream_t stream)
{
    const float* xyzs  = (const float*)d_in[0];
    const float* oxyzs = (const float*)d_in[1];
    const float* feats = (const float*)d_in[2];
    const float* ofeat = (const float*)d_in[3];
    const float* Wt    = (const float*)d_in[4];
    const float* gamma = (const float*)d_in[5];
    const float* beta  = (const float*)d_in[6];
    const float* Ws    = (const float*)d_in[7];
    float* out = (float*)d_out;

    // workspace layout
    char* ws = (char*)d_ws;
    float* tf    = (float*)ws;                                   // 37748736 B (transposed layout)
    float* scale = (float*)(ws + 37748736);                      // 2304 f
    float* shift = scale + 2304;                                 // 2304 f
    int*   fbbuf = (int*)(ws + 37748736 + 18432);                // 344064 i
    float* wbuf  = (float*)(ws + 37748736 + 18432 + 1376256);    // 344064 f
    float* ps    = (float*)(ws + 37748736 + 18432 + 2752512);    // 147456 f
    float* pq    = ps + 147456;                                  // 147456 f

    hipMemcpyAsync(out, oxyzs, (size_t)B_ * L1_ * N1_ * 3 * sizeof(float),
                   hipMemcpyDeviceToDevice, stream);
    float* out_nf = out + (size_t)B_ * L1_ * N1_ * 3;

    tconv_gemm<<<1152, 256, 0, stream>>>(feats, Wt, tf);
    bn_stats1<<<dim3(64, 9), 256, 0, stream>>>(tf, ps, pq);
    bn_stats2<<<9, 256, 0, stream>>>(ps, pq, gamma, beta, scale, shift);
    bn_apply<<<(B_ * L2_ * TFC_ * N2_) / 1024, 256, 0, stream>>>(tf, scale, shift);
    three_nn_kernel<<<dim3(N1_ / 256, L1_, B_), 256, 0, stream>>>(xyzs, oxyzs, fbbuf, wbuf);
    sconv_mfma<<<3584, 256, 0, stream>>>(tf, ofeat, Ws, fbbuf, wbuf, out_nf);
}